// Round 9
// baseline (366.063 us; speedup 1.0000x reference)
//
#include <hip/hip_runtime.h>
#include <hip/hip_bf16.h>
#include <hip/hip_cooperative_groups.h>
#include <math.h>

namespace cg = cooperative_groups;

#define T_ 16
#define B_ 1024
#define F_ 512
#define H_ 128
#define D_ 8
#define C_ 100
#define L_ 512
#define CPAD 128
#define GRID_ 512   // 2 blocks/CU x 256 CU: exactly co-resident at 59 KB LDS

typedef __attribute__((ext_vector_type(8))) short bf16x8_t;
typedef __attribute__((ext_vector_type(4))) float f32x4_t;

__device__ inline ushort f2bf(float x) {
  __hip_bfloat16 b = __float2bfloat16(x);
  return *(ushort*)&b;
}
__device__ inline float bf2f(ushort u) {
  union { unsigned int i; float f; } v;
  v.i = ((unsigned int)u) << 16;
  return v.f;
}

// ---------------------------------------------------------------------------
// k_all: single cooperative kernel.
//   phase A: prep units (feat cvt / W1T / W2T / softmax->lpT), grid-strided
//   phase B: per (32-row tile, tree): h=relu(feat@W1+b1) -> p=sigmoid(h@W2+b2)
//            -> routing (mu in regs) -> part = mu @ lpT^T       [R7 body]
//   phase C: out = log(sum_t part / (L*T))
// LDS 59008 B -> 2 blocks/CU. grid 512 x 256.
// ---------------------------------------------------------------------------
__global__ __launch_bounds__(256) void k_all(
    const float* __restrict__ feat, const float* __restrict__ W1,
    const float* __restrict__ b1, const float* __restrict__ W2,
    const float* __restrict__ b2, const float* __restrict__ pi,
    ushort* __restrict__ feat_bf, ushort* __restrict__ W1T,
    ushort* __restrict__ W2T, ushort* __restrict__ lpT,
    float* __restrict__ part, float* __restrict__ out) {
  __shared__ ushort sm[29504];                          // 59008 B
  const int bid = blockIdx.x, tid = threadIdx.x;

  // ================= phase A: prep =================
  for (int u = bid; u < 2432; u += GRID_) {
    if (u < 256) {  // ---- feat cvt
      int i = (u * 256 + tid) * 8;
      float4 a = *(const float4*)(feat + i);
      float4 b = *(const float4*)(feat + i + 4);
      bf16x8_t o;
      o[0] = (short)f2bf(a.x); o[1] = (short)f2bf(a.y);
      o[2] = (short)f2bf(a.z); o[3] = (short)f2bf(a.w);
      o[4] = (short)f2bf(b.x); o[5] = (short)f2bf(b.y);
      o[6] = (short)f2bf(b.z); o[7] = (short)f2bf(b.w);
      *(bf16x8_t*)(feat_bf + i) = o;
    } else if (u < 2304) {  // ---- weight transposes
      __syncthreads();      // WAR vs previous unit's LDS reads
      float (*tile)[33] = (float(*)[33])sm;
      const float* X; ushort* XT; int K, N, kb, nb, s;
      if (u < 1280) {
        int r = u - 256;  kb = r & 15; nb = (r >> 4) & 3;  s = r >> 6;
        X = W1; XT = W1T; K = F_; N = H_;
      } else {
        int r = u - 1280; kb = r & 3;  nb = (r >> 2) & 15; s = r >> 6;
        X = W2; XT = W2T; K = H_; N = L_;
      }
      const int k0 = kb * 32, n0 = nb * 32;
      const int c = tid & 31, r0 = tid >> 5;
      const float* Xs = X + (size_t)s * K * N;
      ushort* XTs = XT + (size_t)s * N * K;
#pragma unroll
      for (int j = 0; j < 4; ++j)
        tile[r0 + 8 * j][c] = Xs[(size_t)(k0 + r0 + 8 * j) * N + n0 + c];
      __syncthreads();
#pragma unroll
      for (int j = 0; j < 4; ++j)
        XTs[(size_t)(n0 + r0 + 8 * j) * K + k0 + c] = f2bf(tile[c][r0 + 8 * j]);
    } else {  // ---- softmax + transpose to lpT[t][c][l]
      __syncthreads();
      ushort (*ts)[130] = (ushort(*)[130])sm;  // 64 x 130 = 16640 B
      const int idx = u - 2304;
      const int R0 = idx * 64;
      const int t = R0 >> 9, li0 = R0 & 511;
      const int wave = tid >> 6, lane = tid & 63;
      for (int it = 0; it < 16; ++it) {
        int r = wave * 16 + it;
        const float* x = pi + (size_t)(R0 + r) * C_;
        float v0 = (lane < C_) ? x[lane] : -1e30f;
        float v1 = (lane + 64 < C_) ? x[lane + 64] : -1e30f;
        float m = fmaxf(v0, v1);
#pragma unroll
        for (int off = 32; off; off >>= 1) m = fmaxf(m, __shfl_xor(m, off, 64));
        float e0 = __expf(v0 - m);
        float e1 = (lane + 64 < C_) ? __expf(v1 - m) : 0.0f;
        float s = e0 + e1;
#pragma unroll
        for (int off = 32; off; off >>= 1) s += __shfl_xor(s, off, 64);
        float inv = 1.0f / s;
        ts[r][lane]      = (lane < C_) ? f2bf(e0 * inv) : (ushort)0;
        ts[r][lane + 64] = (lane + 64 < C_) ? f2bf(e1 * inv) : (ushort)0;
      }
      __syncthreads();
      int c = tid >> 1, hf = tid & 1;
      ushort tmp[32];
#pragma unroll
      for (int j = 0; j < 32; ++j) tmp[j] = ts[hf * 32 + j][c];
      ushort* dst = lpT + ((size_t)t * CPAD + c) * L_ + li0 + hf * 32;
#pragma unroll
      for (int j = 0; j < 4; ++j)
        *(bf16x8_t*)(dst + 8 * j) = *(bf16x8_t*)&tmp[8 * j];
    }
  }
  __threadfence();
  cg::this_grid().sync();

  // ================= phase B: fused forest (M=32 per block) =================
  {
    ushort (*a_s)[72]  = (ushort(*)[72]) sm;              // ph1 @[0,2304)
    ushort (*b_s)[72]  = (ushort(*)[72])(sm + 2304);      // ph1 @[2304,11520)
    ushort* p_s        = sm;                              // ph2-3 [32][514]
    ushort (*h_s)[136] = (ushort(*)[136])(sm + 16448);    // @[16448,20800)
    ushort (*w_s)[136] = (ushort(*)[136])(sm + 20800);    // ph2 @[20800,29504)
    ushort (*lp_s)[72] = (ushort(*)[72])(sm + 16448);     // ph4 @[16448,25664)
    ushort (*mu_x)[72] = (ushort(*)[72])(sm + 25664);     // ph4 @[25664,27968)

    const int t = bid >> 5, b0 = (bid & 31) * 32;
    const int w = tid >> 6, lane = tid & 63, quad = lane >> 4, n = lane & 15;

    // ---- phase 1: h tile (M=32, N=128, K=512)
    {
      f32x4_t acc[2][2];
#pragma unroll
      for (int i = 0; i < 2; ++i)
#pragma unroll
        for (int j = 0; j < 2; ++j) acc[i][j] = (f32x4_t){0.f, 0.f, 0.f, 0.f};

      for (int kc = 0; kc < 8; ++kc) {
        __syncthreads();
        {
          int row = tid >> 3, col8 = (tid & 7) * 8;
          *(bf16x8_t*)&a_s[row][col8] =
              *(const bf16x8_t*)(feat_bf + (size_t)(b0 + row) * F_ + kc * 64 + col8);
        }
#pragma unroll
        for (int i = 0; i < 4; ++i) {
          int idx = i * 256 + tid;
          int row = idx >> 3, col8 = (idx & 7) * 8;
          *(bf16x8_t*)&b_s[row][col8] =
              *(const bf16x8_t*)(W1T + ((size_t)t * H_ + row) * F_ + kc * 64 + col8);
        }
        __syncthreads();
#pragma unroll
        for (int ks = 0; ks < 64; ks += 32) {
          bf16x8_t af[2], bfr[2];
#pragma unroll
          for (int mt = 0; mt < 2; ++mt)
            af[mt] = *(const bf16x8_t*)&a_s[mt * 16 + n][ks + quad * 8];
#pragma unroll
          for (int nt = 0; nt < 2; ++nt)
            bfr[nt] = *(const bf16x8_t*)&b_s[w * 32 + nt * 16 + n][ks + quad * 8];
#pragma unroll
          for (int mt = 0; mt < 2; ++mt)
#pragma unroll
            for (int nt = 0; nt < 2; ++nt)
              acc[mt][nt] = __builtin_amdgcn_mfma_f32_16x16x32_bf16(
                  af[mt], bfr[nt], acc[mt][nt], 0, 0, 0);
        }
      }
      float bias[2] = {b1[t * H_ + w * 32 + n], b1[t * H_ + w * 32 + 16 + n]};
      __syncthreads();   // a_s/b_s dead; h_s write below is disjoint
#pragma unroll
      for (int mt = 0; mt < 2; ++mt)
#pragma unroll
        for (int nt = 0; nt < 2; ++nt)
#pragma unroll
          for (int r = 0; r < 4; ++r) {
            int row = mt * 16 + quad * 4 + r;
            int col = w * 32 + nt * 16 + n;
            float v = acc[mt][nt][r] + bias[nt];
            h_s[row][col] = f2bf(v > 0.f ? v : 0.f);
          }
    }

    // ---- phase 2: GEMM2 + sigmoid -> p_s
    for (int nc = 0; nc < 8; ++nc) {
      __syncthreads();
#pragma unroll
      for (int i = 0; i < 4; ++i) {
        int idx = i * 256 + tid;
        int row = idx >> 4, col8 = (idx & 15) * 8;
        *(bf16x8_t*)&w_s[row][col8] =
            *(const bf16x8_t*)(W2T + ((size_t)t * L_ + nc * 64 + row) * H_ + col8);
      }
      __syncthreads();
      f32x4_t acc[2];
      acc[0] = (f32x4_t){0.f, 0.f, 0.f, 0.f};
      acc[1] = (f32x4_t){0.f, 0.f, 0.f, 0.f};
#pragma unroll
      for (int ks = 0; ks < 128; ks += 32) {
        bf16x8_t bfrag = *(const bf16x8_t*)&w_s[w * 16 + n][ks + quad * 8];
#pragma unroll
        for (int mt = 0; mt < 2; ++mt) {
          bf16x8_t afrag = *(const bf16x8_t*)&h_s[mt * 16 + n][ks + quad * 8];
          acc[mt] = __builtin_amdgcn_mfma_f32_16x16x32_bf16(afrag, bfrag,
                                                            acc[mt], 0, 0, 0);
        }
      }
      int l = nc * 64 + w * 16 + n;
      float bias = b2[t * L_ + l];
#pragma unroll
      for (int mt = 0; mt < 2; ++mt)
#pragma unroll
        for (int r = 0; r < 4; ++r) {
          float x = acc[mt][r] + bias;
          p_s[(mt * 16 + quad * 4 + r) * 514 + l] = f2bf(1.0f / (1.0f + __expf(-x)));
        }
    }
    __syncthreads();

    // ---- routing: mu -> registers
    bf16x8_t muv[4][2];
#pragma unroll
    for (int pass = 0; pass < 4; ++pass) {
      int b = pass * 8 + (tid >> 5);
      int s = tid & 31;
      float P = 1.f;
#pragma unroll
      for (int d = 0; d < 5; ++d) {
        int nd = (1 << d) - 1 + (s >> (5 - d));
        int sd = (s >> (4 - d)) & 1;
        float pv = bf2f(p_s[b * 514 + nd]);
        P *= sd ? (1.f - pv) : pv;
      }
      float p5 = bf2f(p_s[b * 514 + 31 + s]);
      float q5[2] = {P * p5, P * (1.f - p5)};
      float q6[4], q7[8];
#pragma unroll
      for (int j = 0; j < 2; ++j) {
        float pv = bf2f(p_s[b * 514 + 63 + 2 * s + j]);
        q6[2 * j] = q5[j] * pv;
        q6[2 * j + 1] = q5[j] * (1.f - pv);
      }
#pragma unroll
      for (int uu = 0; uu < 4; ++uu) {
        float pv = bf2f(p_s[b * 514 + 127 + 4 * s + uu]);
        q7[2 * uu] = q6[uu] * pv;
        q7[2 * uu + 1] = q6[uu] * (1.f - pv);
      }
      bf16x8_t o0, o1;
#pragma unroll
      for (int v = 0; v < 8; ++v) {
        float pv = bf2f(p_s[b * 514 + 255 + 8 * s + v]);
        ushort e0 = f2bf(q7[v] * pv);
        ushort e1 = f2bf(q7[v] * (1.f - pv));
        if (v < 4) { o0[2 * v] = (short)e0; o0[2 * v + 1] = (short)e1; }
        else       { o1[2 * (v - 4)] = (short)e0; o1[2 * (v - 4) + 1] = (short)e1; }
      }
      muv[pass][0] = o0;
      muv[pass][1] = o1;
    }

    // ---- phase 4: mix part = mu @ lpT^T
    f32x4_t acc4[2][2];
#pragma unroll
    for (int i = 0; i < 2; ++i)
#pragma unroll
      for (int j = 0; j < 2; ++j) acc4[i][j] = (f32x4_t){0.f, 0.f, 0.f, 0.f};

    const ushort* lpt_t = lpT + (size_t)t * CPAD * L_;
    for (int c = 0; c < 8; ++c) {
      {  // stage lp chunk: 128 class-rows x 64 l
        int row = tid >> 1, hf = tid & 1;
        const ushort* src = lpt_t + (size_t)row * L_ + c * 64 + hf * 32;
#pragma unroll
        for (int j = 0; j < 4; ++j)
          *(bf16x8_t*)&lp_s[row][hf * 32 + 8 * j] = *(const bf16x8_t*)(src + 8 * j);
      }
      if (((tid & 31) >> 2) == c) {  // deposit this chunk's mu from registers
        int sub = tid & 3;
#pragma unroll
        for (int pass = 0; pass < 4; ++pass) {
          int b = pass * 8 + (tid >> 5);
          *(bf16x8_t*)&mu_x[b][sub * 16]     = muv[pass][0];
          *(bf16x8_t*)&mu_x[b][sub * 16 + 8] = muv[pass][1];
        }
      }
      __syncthreads();
#pragma unroll
      for (int ks = 0; ks < 64; ks += 32) {
        bf16x8_t af[2], bfr[2];
#pragma unroll
        for (int mt = 0; mt < 2; ++mt)
          af[mt] = *(const bf16x8_t*)&mu_x[mt * 16 + n][ks + quad * 8];
#pragma unroll
        for (int nt = 0; nt < 2; ++nt)
          bfr[nt] = *(const bf16x8_t*)&lp_s[w * 32 + nt * 16 + n][ks + quad * 8];
#pragma unroll
        for (int mt = 0; mt < 2; ++mt)
#pragma unroll
          for (int nt = 0; nt < 2; ++nt)
            acc4[mt][nt] = __builtin_amdgcn_mfma_f32_16x16x32_bf16(
                af[mt], bfr[nt], acc4[mt][nt], 0, 0, 0);
      }
      __syncthreads();
    }
#pragma unroll
    for (int mt = 0; mt < 2; ++mt)
#pragma unroll
      for (int nt = 0; nt < 2; ++nt) {
        int cc = w * 32 + nt * 16 + n;
        if (cc < C_) {
#pragma unroll
          for (int r = 0; r < 4; ++r) {
            int m = b0 + mt * 16 + quad * 4 + r;
            part[((size_t)t * B_ + m) * C_ + cc] = acc4[mt][nt][r];
          }
        }
      }
  }
  __threadfence();
  cg::this_grid().sync();

  // ================= phase C: final log =================
  {
    int i = bid * 256 + tid;
    if (i < B_ * C_) {
      float s = 0.0f;
#pragma unroll
      for (int t = 0; t < T_; ++t) s += part[(size_t)t * B_ * C_ + i];
      out[i] = logf(s * (1.0f / (L_ * T_)));
    }
  }
}

extern "C" void kernel_launch(void* const* d_in, const int* in_sizes, int n_in,
                              void* d_out, int out_size, void* d_ws,
                              size_t ws_size, hipStream_t stream) {
  const float* feat = (const float*)d_in[0];
  const float* W1   = (const float*)d_in[1];
  const float* b1   = (const float*)d_in[2];
  const float* W2   = (const float*)d_in[3];
  const float* b2   = (const float*)d_in[4];
  const float* pi   = (const float*)d_in[5];
  float* out = (float*)d_out;

  char* ws = (char*)d_ws;
  // Disjoint regions, no aliasing: total 13.25 MB.
  ushort* feat_bf = (ushort*)(ws);                              // 1 MB
  ushort* W1T_buf = (ushort*)(ws + ((size_t)1 << 20));          // 2 MB
  ushort* W2T_buf = (ushort*)(ws + ((size_t)3 << 20));          // 2 MB
  ushort* lpT_buf = (ushort*)(ws + ((size_t)5 << 20));          // 2 MB
  float*  part_buf = (float*)(ws + ((size_t)7 << 20));          // 6.25 MB

  void* args[] = {
      (void*)&feat, (void*)&W1, (void*)&b1, (void*)&W2, (void*)&b2,
      (void*)&pi,   (void*)&feat_bf, (void*)&W1T_buf, (void*)&W2T_buf,
      (void*)&lpT_buf, (void*)&part_buf, (void*)&out};
  hipLaunchCooperativeKernel((const void*)k_all, dim3(GRID_), dim3(256),
                             args, 0, stream);
}

// Round 10
// 124.772 us; speedup vs baseline: 2.9338x; 2.9338x over previous
//
#include <hip/hip_runtime.h>
#include <hip/hip_bf16.h>
#include <math.h>

#define T_ 16
#define B_ 1024
#define F_ 512
#define H_ 128
#define D_ 8
#define C_ 100
#define L_ 512
#define CPAD 128   // classes padded to 128 (zeros) for vectorized MFMA staging

typedef __attribute__((ext_vector_type(8))) short bf16x8_t;
typedef __attribute__((ext_vector_type(4))) float f32x4_t;

__device__ inline ushort f2bf(float x) {
  __hip_bfloat16 b = __float2bfloat16(x);
  return *(ushort*)&b;
}
__device__ inline float bf2f(ushort u) {
  union { unsigned int i; float f; } v;
  v.i = ((unsigned int)u) << 16;
  return v.f;
}

// ---------------------------------------------------------------------------
// k_prep: fused preprocessing, block-range dispatch (2432 blocks).
//   [0,256)      : feat fp32 -> bf16
//   [256,1280)   : W1 [t][F][H] -> W1T [t][H][F] bf16
//   [1280,2304)  : W2 [t][H][L] -> W2T [t][L][H] bf16
//   [2304,2432)  : leaf_p = softmax(pi) -> lpT [t][c=128][l=512] bf16
// ---------------------------------------------------------------------------
__global__ __launch_bounds__(256) void k_prep(
    const float* __restrict__ feat, const float* __restrict__ W1,
    const float* __restrict__ W2, const float* __restrict__ pi,
    ushort* __restrict__ feat_bf, ushort* __restrict__ W1T,
    ushort* __restrict__ W2T, ushort* __restrict__ lpT) {
  __shared__ ushort sm[8320];
  const int bid = blockIdx.x, tid = threadIdx.x;

  if (bid < 256) {  // ---- feat cvt
    int i = (bid * 256 + tid) * 8;
    float4 a = *(const float4*)(feat + i);
    float4 b = *(const float4*)(feat + i + 4);
    bf16x8_t o;
    o[0] = (short)f2bf(a.x); o[1] = (short)f2bf(a.y);
    o[2] = (short)f2bf(a.z); o[3] = (short)f2bf(a.w);
    o[4] = (short)f2bf(b.x); o[5] = (short)f2bf(b.y);
    o[6] = (short)f2bf(b.z); o[7] = (short)f2bf(b.w);
    *(bf16x8_t*)(feat_bf + i) = o;
    return;
  }
  if (bid < 2304) {  // ---- weight transposes
    float (*tile)[33] = (float(*)[33])sm;
    const float* X; ushort* XT; int K, N, kb, nb, s;
    if (bid < 1280) {
      int r = bid - 256;  kb = r & 15; nb = (r >> 4) & 3;  s = r >> 6;
      X = W1; XT = W1T; K = F_; N = H_;
    } else {
      int r = bid - 1280; kb = r & 3;  nb = (r >> 2) & 15; s = r >> 6;
      X = W2; XT = W2T; K = H_; N = L_;
    }
    const int k0 = kb * 32, n0 = nb * 32;
    const int c = tid & 31, r0 = tid >> 5;
    const float* Xs = X + (size_t)s * K * N;
    ushort* XTs = XT + (size_t)s * N * K;
#pragma unroll
    for (int j = 0; j < 4; ++j)
      tile[r0 + 8 * j][c] = Xs[(size_t)(k0 + r0 + 8 * j) * N + n0 + c];
    __syncthreads();
#pragma unroll
    for (int j = 0; j < 4; ++j)
      XTs[(size_t)(n0 + r0 + 8 * j) * K + k0 + c] = f2bf(tile[c][r0 + 8 * j]);
    return;
  }
  {  // ---- softmax + transpose to lpT[t][c][l]
    ushort (*ts)[130] = (ushort(*)[130])sm;  // 64 x 130
    const int idx = bid - 2304;
    const int R0 = idx * 64;
    const int t = R0 >> 9, li0 = R0 & 511;
    const int wave = tid >> 6, lane = tid & 63;
    for (int it = 0; it < 16; ++it) {
      int r = wave * 16 + it;
      const float* x = pi + (size_t)(R0 + r) * C_;
      float v0 = (lane < C_) ? x[lane] : -1e30f;
      float v1 = (lane + 64 < C_) ? x[lane + 64] : -1e30f;
      float m = fmaxf(v0, v1);
#pragma unroll
      for (int off = 32; off; off >>= 1) m = fmaxf(m, __shfl_xor(m, off, 64));
      float e0 = __expf(v0 - m);
      float e1 = (lane + 64 < C_) ? __expf(v1 - m) : 0.0f;
      float s = e0 + e1;
#pragma unroll
      for (int off = 32; off; off >>= 1) s += __shfl_xor(s, off, 64);
      float inv = 1.0f / s;
      ts[r][lane]      = (lane < C_) ? f2bf(e0 * inv) : (ushort)0;
      ts[r][lane + 64] = (lane + 64 < C_) ? f2bf(e1 * inv) : (ushort)0;
    }
    __syncthreads();
    int c = tid >> 1, hf = tid & 1;
    ushort tmp[32];
#pragma unroll
    for (int j = 0; j < 32; ++j) tmp[j] = ts[hf * 32 + j][c];
    ushort* dst = lpT + ((size_t)t * CPAD + c) * L_ + li0 + hf * 32;
#pragma unroll
    for (int j = 0; j < 4; ++j)
      *(bf16x8_t*)(dst + 8 * j) = *(bf16x8_t*)&tmp[8 * j];
  }
}

// ---------------------------------------------------------------------------
// k12: fused GEMM1 (h in LDS) + GEMM2 + sigmoid + tree-factored routing ->
// mu bf16 (global).  grid (B/32=32, T), 256 thr.  [R6-verified body]
// LDS union 59392 B: h_s persists; phase-1 a_s/b_s alias phase-2 w_s/p_s.
// ---------------------------------------------------------------------------
__global__ __launch_bounds__(256) void k12_mfma(
    const ushort* __restrict__ feat, const ushort* __restrict__ W1T,
    const float* __restrict__ b1, const ushort* __restrict__ W2T,
    const float* __restrict__ b2, ushort* __restrict__ mu) {
  __shared__ ushort smem[29696];                        // 59392 B
  ushort (*h_s)[136] = (ushort(*)[136])smem;            // [32][136] @0
  ushort (*a_s)[72]  = (ushort(*)[72])(smem + 4352);    // [32][72]  ph1
  ushort (*b_s)[72]  = (ushort(*)[72])(smem + 6656);    // [128][72] ph1
  ushort (*w_s)[136] = (ushort(*)[136])(smem + 4352);   // [64][136] ph2
  ushort (*p_s)[520] = (ushort(*)[520])(smem + 13056);  // [32][520] ph2

  const int t = blockIdx.y, b0 = blockIdx.x * 32, tid = threadIdx.x;
  const int w = tid >> 6, lane = tid & 63, quad = lane >> 4, n = lane & 15;

  // ---------------- phase 1: h tile (M=32, N=128, K=512) ----------------
  {
    f32x4_t acc[2][2];
#pragma unroll
    for (int i = 0; i < 2; ++i)
#pragma unroll
      for (int j = 0; j < 2; ++j) acc[i][j] = (f32x4_t){0.f, 0.f, 0.f, 0.f};

    for (int kc = 0; kc < 8; ++kc) {
      __syncthreads();
      {
        int row = tid >> 3, col8 = (tid & 7) * 8;
        *(bf16x8_t*)&a_s[row][col8] =
            *(const bf16x8_t*)(feat + (size_t)(b0 + row) * F_ + kc * 64 + col8);
      }
#pragma unroll
      for (int i = 0; i < 4; ++i) {
        int idx = i * 256 + tid;
        int row = idx >> 3, col8 = (idx & 7) * 8;
        *(bf16x8_t*)&b_s[row][col8] =
            *(const bf16x8_t*)(W1T + ((size_t)t * H_ + row) * F_ + kc * 64 + col8);
      }
      __syncthreads();
#pragma unroll
      for (int ks = 0; ks < 64; ks += 32) {
        bf16x8_t af[2], bfr[2];
#pragma unroll
        for (int mt = 0; mt < 2; ++mt)
          af[mt] = *(const bf16x8_t*)&a_s[mt * 16 + n][ks + quad * 8];
#pragma unroll
        for (int nt = 0; nt < 2; ++nt)
          bfr[nt] = *(const bf16x8_t*)&b_s[w * 32 + nt * 16 + n][ks + quad * 8];
#pragma unroll
        for (int mt = 0; mt < 2; ++mt)
#pragma unroll
          for (int nt = 0; nt < 2; ++nt)
            acc[mt][nt] = __builtin_amdgcn_mfma_f32_16x16x32_bf16(
                af[mt], bfr[nt], acc[mt][nt], 0, 0, 0);
      }
    }
    float bias[2] = {b1[t * H_ + w * 32 + n], b1[t * H_ + w * 32 + 16 + n]};
    __syncthreads();   // a_s/b_s dead; h_s region write below is disjoint
#pragma unroll
    for (int mt = 0; mt < 2; ++mt)
#pragma unroll
      for (int nt = 0; nt < 2; ++nt)
#pragma unroll
        for (int r = 0; r < 4; ++r) {
          int row = mt * 16 + quad * 4 + r;
          int col = w * 32 + nt * 16 + n;
          float v = acc[mt][nt][r] + bias[nt];
          h_s[row][col] = f2bf(v > 0.f ? v : 0.f);
        }
  }

  // ---------------- phase 2: GEMM2 + sigmoid -> p_s ----------------
  for (int nc = 0; nc < 8; ++nc) {
    __syncthreads();
#pragma unroll
    for (int i = 0; i < 4; ++i) {
      int idx = i * 256 + tid;
      int row = idx >> 4, col8 = (idx & 15) * 8;
      *(bf16x8_t*)&w_s[row][col8] =
          *(const bf16x8_t*)(W2T + ((size_t)t * L_ + nc * 64 + row) * H_ + col8);
    }
    __syncthreads();
    f32x4_t acc[2];
    acc[0] = (f32x4_t){0.f, 0.f, 0.f, 0.f};
    acc[1] = (f32x4_t){0.f, 0.f, 0.f, 0.f};
#pragma unroll
    for (int ks = 0; ks < 128; ks += 32) {
      bf16x8_t bfrag = *(const bf16x8_t*)&w_s[w * 16 + n][ks + quad * 8];
#pragma unroll
      for (int mt = 0; mt < 2; ++mt) {
        bf16x8_t afrag = *(const bf16x8_t*)&h_s[mt * 16 + n][ks + quad * 8];
        acc[mt] = __builtin_amdgcn_mfma_f32_16x16x32_bf16(afrag, bfrag,
                                                          acc[mt], 0, 0, 0);
      }
    }
    int l = nc * 64 + w * 16 + n;
    float bias = b2[t * L_ + l];
#pragma unroll
    for (int mt = 0; mt < 2; ++mt)
#pragma unroll
      for (int r = 0; r < 4; ++r) {
        float x = acc[mt][r] + bias;
        p_s[mt * 16 + quad * 4 + r][l] = f2bf(1.0f / (1.0f + __expf(-x)));
      }
  }
  __syncthreads();

  // ---------------- routing: (row b, 16-leaf subtree s) ----------------
#pragma unroll
  for (int pass = 0; pass < 4; ++pass) {
    int b = pass * 8 + (tid >> 5);
    int s = tid & 31;
    float P = 1.f;
#pragma unroll
    for (int d = 0; d < 5; ++d) {
      int nd = (1 << d) - 1 + (s >> (5 - d));
      int sd = (s >> (4 - d)) & 1;
      float pv = bf2f(p_s[b][nd]);
      P *= sd ? (1.f - pv) : pv;
    }
    float p5 = bf2f(p_s[b][31 + s]);
    float q5[2] = {P * p5, P * (1.f - p5)};
    float q6[4], q7[8];
#pragma unroll
    for (int j = 0; j < 2; ++j) {
      float pv = bf2f(p_s[b][63 + 2 * s + j]);
      q6[2 * j] = q5[j] * pv;
      q6[2 * j + 1] = q5[j] * (1.f - pv);
    }
#pragma unroll
    for (int u = 0; u < 4; ++u) {
      float pv = bf2f(p_s[b][127 + 4 * s + u]);
      q7[2 * u] = q6[u] * pv;
      q7[2 * u + 1] = q6[u] * (1.f - pv);
    }
    bf16x8_t o0, o1;
#pragma unroll
    for (int v = 0; v < 8; ++v) {
      float pv = bf2f(p_s[b][255 + 8 * s + v]);
      ushort e0 = f2bf(q7[v] * pv);
      ushort e1 = f2bf(q7[v] * (1.f - pv));
      if (v < 4) { o0[2 * v] = (short)e0; o0[2 * v + 1] = (short)e1; }
      else       { o1[2 * (v - 4)] = (short)e0; o1[2 * (v - 4) + 1] = (short)e1; }
    }
    ushort* dst = mu + ((size_t)t * B_ + b0 + b) * L_ + s * 16;
    *(bf16x8_t*)dst = o0;
    *(bf16x8_t*)(dst + 8) = o1;
  }
}

// ---------------------------------------------------------------------------
// k5: MFMA mix with VECTORIZED B-staging from lpT[t][c][l].
// grid (B/32=32, T), 256 thr (4 waves). M=32 (mt 2), classes: wave w covers
// [w*32, w*32+32) (nt 2). mu (A) direct from global; lp chunk staged 16B.
// LDS 36864 B -> 4 blocks/CU.
// ---------------------------------------------------------------------------
__global__ __launch_bounds__(256) void k5_mfma(
    const ushort* __restrict__ mu, const ushort* __restrict__ lpT,
    float* __restrict__ part) {
  __shared__ ushort lp_s[CPAD][72];   // [class][64-l chunk], pitch 144 B
  const int t = blockIdx.y, m0 = blockIdx.x * 32, tid = threadIdx.x;
  const int w = tid >> 6, lane = tid & 63, quad = lane >> 4, n = lane & 15;

  f32x4_t acc[2][2];
#pragma unroll
  for (int i = 0; i < 2; ++i)
#pragma unroll
    for (int j = 0; j < 2; ++j) acc[i][j] = (f32x4_t){0.f, 0.f, 0.f, 0.f};

  const ushort* lpt_t  = lpT + (size_t)t * CPAD * L_;
  const ushort* muBase = mu + ((size_t)t * B_ + m0) * L_;

  for (int c = 0; c < 8; ++c) {
    __syncthreads();   // WAR: prior MFMA reads of lp_s done
    {  // stage lp chunk: 128 class-rows x 64 l, pure 16B copies
      int row = tid >> 1, hf = tid & 1;
      const ushort* src = lpt_t + (size_t)row * L_ + c * 64 + hf * 32;
#pragma unroll
      for (int j = 0; j < 4; ++j)
        *(bf16x8_t*)&lp_s[row][hf * 32 + 8 * j] = *(const bf16x8_t*)(src + 8 * j);
    }
    __syncthreads();
#pragma unroll
    for (int ks = 0; ks < 64; ks += 32) {
      bf16x8_t af[2], bfr[2];
#pragma unroll
      for (int mt = 0; mt < 2; ++mt)
        af[mt] = *(const bf16x8_t*)(muBase + (size_t)(mt * 16 + n) * L_ +
                                    c * 64 + ks + quad * 8);
#pragma unroll
      for (int nt = 0; nt < 2; ++nt)
        bfr[nt] = *(const bf16x8_t*)&lp_s[w * 32 + nt * 16 + n][ks + quad * 8];
#pragma unroll
      for (int mt = 0; mt < 2; ++mt)
#pragma unroll
        for (int nt = 0; nt < 2; ++nt)
          acc[mt][nt] = __builtin_amdgcn_mfma_f32_16x16x32_bf16(
              af[mt], bfr[nt], acc[mt][nt], 0, 0, 0);
    }
  }
  // C/D: col = lane&15 (class within 16-tile), row = quad*4 + r
#pragma unroll
  for (int mt = 0; mt < 2; ++mt)
#pragma unroll
    for (int nt = 0; nt < 2; ++nt) {
      int cc = w * 32 + nt * 16 + n;
      if (cc < C_) {
#pragma unroll
        for (int r = 0; r < 4; ++r) {
          int m = m0 + mt * 16 + quad * 4 + r;
          part[((size_t)t * B_ + m) * C_ + cc] = acc[mt][nt][r];
        }
      }
    }
}

// ---------------------------------------------------------------------------
// k6: out[b][c] = log( (sum_t part[t][b][c]) / (L*T) )
// ---------------------------------------------------------------------------
__global__ __launch_bounds__(256) void k6_log(
    const float* __restrict__ part, float* __restrict__ out) {
  int i = blockIdx.x * 256 + threadIdx.x;
  if (i < B_ * C_) {
    float s = 0.0f;
#pragma unroll
    for (int t = 0; t < T_; ++t) s += part[(size_t)t * B_ * C_ + i];
    out[i] = logf(s * (1.0f / (L_ * T_)));
  }
}

extern "C" void kernel_launch(void* const* d_in, const int* in_sizes, int n_in,
                              void* d_out, int out_size, void* d_ws,
                              size_t ws_size, hipStream_t stream) {
  const float* feat = (const float*)d_in[0];
  const float* W1   = (const float*)d_in[1];
  const float* b1   = (const float*)d_in[2];
  const float* W2   = (const float*)d_in[3];
  const float* b2   = (const float*)d_in[4];
  const float* pi   = (const float*)d_in[5];
  float* out = (float*)d_out;

  char* ws = (char*)d_ws;
  // Disjoint regions, no aliasing: total 29.25 MB.
  ushort* feat_bf = (ushort*)(ws);                              // 1 MB
  ushort* W1T_buf = (ushort*)(ws + ((size_t)1 << 20));          // 2 MB
  ushort* W2T_buf = (ushort*)(ws + ((size_t)3 << 20));          // 2 MB
  ushort* lpT_buf = (ushort*)(ws + ((size_t)5 << 20));          // 2 MB
  ushort* mu_buf  = (ushort*)(ws + ((size_t)7 << 20));          // 16 MB
  float*  part_buf = (float*)(ws + ((size_t)23 << 20));         // 6.25 MB

  k_prep<<<2432, 256, 0, stream>>>(feat, W1, W2, pi, feat_bf, W1T_buf,
                                   W2T_buf, lpT_buf);
  k12_mfma<<<dim3(B_ / 32, T_), 256, 0, stream>>>(feat_bf, W1T_buf, b1,
                                                  W2T_buf, b2, mu_buf);
  k5_mfma<<<dim3(B_ / 32, T_), 256, 0, stream>>>(mu_buf, lpT_buf, part_buf);
  k6_log<<<(B_ * C_ + 255) / 256, 256, 0, stream>>>(part_buf, out);
}

// Round 11
// 115.766 us; speedup vs baseline: 3.1621x; 1.0778x over previous
//
#include <hip/hip_runtime.h>
#include <hip/hip_bf16.h>
#include <math.h>

#define T_ 16
#define B_ 1024
#define F_ 512
#define H_ 128
#define D_ 8
#define C_ 100
#define L_ 512
#define CP_ 112   // C padded to multiple of 16 for MFMA N

typedef __attribute__((ext_vector_type(8))) short bf16x8_t;
typedef __attribute__((ext_vector_type(4))) short bf16x4_t;
typedef __attribute__((ext_vector_type(4))) float f32x4_t;

__device__ inline ushort f2bf(float x) {
  __hip_bfloat16 b = __float2bfloat16(x);
  return *(ushort*)&b;
}
__device__ inline float bf2f(ushort u) {
  union { unsigned int i; float f; } v;
  v.i = ((unsigned int)u) << 16;
  return v.f;
}

// ---------------------------------------------------------------------------
// k_prep: fused independent preprocessing, block-range dispatch.
//   [0,256)      : feat fp32 -> bf16
//   [256,1280)   : W1 [t][F][H] -> W1T [t][H][F] bf16
//   [1280,2304)  : W2 [t][H][L] -> W2T [t][L][H] bf16
//   [2304,4352)  : leaf_p = softmax(pi) -> bf16 padded CP_
// ---------------------------------------------------------------------------
__global__ __launch_bounds__(256) void k_prep(
    const float* __restrict__ feat, const float* __restrict__ W1,
    const float* __restrict__ W2, const float* __restrict__ pi,
    ushort* __restrict__ feat_bf, ushort* __restrict__ W1T,
    ushort* __restrict__ W2T, ushort* __restrict__ lp) {
  __shared__ float tile[32][33];
  const int bid = blockIdx.x, tid = threadIdx.x;

  if (bid < 256) {  // ---- feat cvt
    int i = (bid * 256 + tid) * 8;
    float4 a = *(const float4*)(feat + i);
    float4 b = *(const float4*)(feat + i + 4);
    bf16x8_t o;
    o[0] = (short)f2bf(a.x); o[1] = (short)f2bf(a.y);
    o[2] = (short)f2bf(a.z); o[3] = (short)f2bf(a.w);
    o[4] = (short)f2bf(b.x); o[5] = (short)f2bf(b.y);
    o[6] = (short)f2bf(b.z); o[7] = (short)f2bf(b.w);
    *(bf16x8_t*)(feat_bf + i) = o;
    return;
  }
  if (bid < 2304) {  // ---- weight transposes
    const float* X; ushort* XT; int K, N, kb, nb, s;
    if (bid < 1280) {
      int r = bid - 256;  kb = r & 15; nb = (r >> 4) & 3;  s = r >> 6;
      X = W1; XT = W1T; K = F_; N = H_;
    } else {
      int r = bid - 1280; kb = r & 3;  nb = (r >> 2) & 15; s = r >> 6;
      X = W2; XT = W2T; K = H_; N = L_;
    }
    const int k0 = kb * 32, n0 = nb * 32;
    const int c = tid & 31, r0 = tid >> 5;
    const float* Xs = X + (size_t)s * K * N;
    ushort* XTs = XT + (size_t)s * N * K;
#pragma unroll
    for (int j = 0; j < 4; ++j)
      tile[r0 + 8 * j][c] = Xs[(size_t)(k0 + r0 + 8 * j) * N + n0 + c];
    __syncthreads();
#pragma unroll
    for (int j = 0; j < 4; ++j)
      XTs[(size_t)(n0 + r0 + 8 * j) * K + k0 + c] = f2bf(tile[c][r0 + 8 * j]);
    return;
  }
  {  // ---- softmax rows (4 rows per block, one per wave)
    int row  = (bid - 2304) * 4 + (tid >> 6);
    int lane = tid & 63;
    const float* x = pi + (size_t)row * C_;
    float v0 = (lane < C_) ? x[lane] : -1e30f;
    float v1 = (lane + 64 < C_) ? x[lane + 64] : -1e30f;
    float m = fmaxf(v0, v1);
#pragma unroll
    for (int off = 32; off; off >>= 1) m = fmaxf(m, __shfl_xor(m, off, 64));
    float e0 = __expf(v0 - m);
    float e1 = (lane + 64 < C_) ? __expf(v1 - m) : 0.0f;
    float sm = e0 + e1;
#pragma unroll
    for (int off = 32; off; off >>= 1) sm += __shfl_xor(sm, off, 64);
    float inv = 1.0f / sm;
    size_t base = (size_t)row * CP_;
    if (lane < C_) lp[base + lane] = f2bf(e0 * inv);
    int c2 = lane + 64;
    if (c2 < CP_) lp[base + c2] = f2bf(c2 < C_ ? e1 * inv : 0.0f);
  }
}

// ---------------------------------------------------------------------------
// k12: fused GEMM1 (h = relu(feat@W1+b1), kept in LDS) + GEMM2 + sigmoid +
// tree-factored routing -> mu bf16.  grid (B/32, T), 256 thr.
// LDS union 59392 B: h_s persists; phase-1 a_s/b_s alias phase-2 w_s/p_s.
// ---------------------------------------------------------------------------
__global__ __launch_bounds__(256) void k12_mfma(
    const ushort* __restrict__ feat, const ushort* __restrict__ W1T,
    const float* __restrict__ b1, const ushort* __restrict__ W2T,
    const float* __restrict__ b2, ushort* __restrict__ mu) {
  __shared__ ushort smem[29696];                        // 59392 B
  ushort (*h_s)[136] = (ushort(*)[136])smem;            // [32][136] @0
  ushort (*a_s)[72]  = (ushort(*)[72])(smem + 4352);    // [32][72]  ph1
  ushort (*b_s)[72]  = (ushort(*)[72])(smem + 6656);    // [128][72] ph1
  ushort (*w_s)[136] = (ushort(*)[136])(smem + 4352);   // [64][136] ph2
  ushort (*p_s)[520] = (ushort(*)[520])(smem + 13056);  // [32][520] ph2

  const int t = blockIdx.y, b0 = blockIdx.x * 32, tid = threadIdx.x;
  const int w = tid >> 6, lane = tid & 63, quad = lane >> 4, n = lane & 15;

  // ---------------- phase 1: h tile (M=32, N=128, K=512) ----------------
  {
    f32x4_t acc[2][2];
#pragma unroll
    for (int i = 0; i < 2; ++i)
#pragma unroll
      for (int j = 0; j < 2; ++j) acc[i][j] = (f32x4_t){0.f, 0.f, 0.f, 0.f};

    for (int kc = 0; kc < 8; ++kc) {
      __syncthreads();
      {
        int row = tid >> 3, col8 = (tid & 7) * 8;
        *(bf16x8_t*)&a_s[row][col8] =
            *(const bf16x8_t*)(feat + (size_t)(b0 + row) * F_ + kc * 64 + col8);
      }
#pragma unroll
      for (int i = 0; i < 4; ++i) {
        int idx = i * 256 + tid;
        int row = idx >> 3, col8 = (idx & 7) * 8;
        *(bf16x8_t*)&b_s[row][col8] =
            *(const bf16x8_t*)(W1T + ((size_t)t * H_ + row) * F_ + kc * 64 + col8);
      }
      __syncthreads();
#pragma unroll
      for (int ks = 0; ks < 64; ks += 32) {
        bf16x8_t af[2], bfr[2];
#pragma unroll
        for (int mt = 0; mt < 2; ++mt)
          af[mt] = *(const bf16x8_t*)&a_s[mt * 16 + n][ks + quad * 8];
#pragma unroll
        for (int nt = 0; nt < 2; ++nt)
          bfr[nt] = *(const bf16x8_t*)&b_s[w * 32 + nt * 16 + n][ks + quad * 8];
#pragma unroll
        for (int mt = 0; mt < 2; ++mt)
#pragma unroll
          for (int nt = 0; nt < 2; ++nt)
            acc[mt][nt] = __builtin_amdgcn_mfma_f32_16x16x32_bf16(
                af[mt], bfr[nt], acc[mt][nt], 0, 0, 0);
      }
    }
    float bias[2] = {b1[t * H_ + w * 32 + n], b1[t * H_ + w * 32 + 16 + n]};
    __syncthreads();   // a_s/b_s dead; h_s region write below is disjoint
#pragma unroll
    for (int mt = 0; mt < 2; ++mt)
#pragma unroll
      for (int nt = 0; nt < 2; ++nt)
#pragma unroll
        for (int r = 0; r < 4; ++r) {
          int row = mt * 16 + quad * 4 + r;
          int col = w * 32 + nt * 16 + n;
          float v = acc[mt][nt][r] + bias[nt];
          h_s[row][col] = f2bf(v > 0.f ? v : 0.f);
        }
  }

  // ---------------- phase 2: GEMM2 + sigmoid -> p_s ----------------
  for (int nc = 0; nc < 8; ++nc) {
    __syncthreads();
#pragma unroll
    for (int i = 0; i < 4; ++i) {
      int idx = i * 256 + tid;
      int row = idx >> 4, col8 = (idx & 15) * 8;
      *(bf16x8_t*)&w_s[row][col8] =
          *(const bf16x8_t*)(W2T + ((size_t)t * L_ + nc * 64 + row) * H_ + col8);
    }
    __syncthreads();
    f32x4_t acc[2];
    acc[0] = (f32x4_t){0.f, 0.f, 0.f, 0.f};
    acc[1] = (f32x4_t){0.f, 0.f, 0.f, 0.f};
#pragma unroll
    for (int ks = 0; ks < 128; ks += 32) {
      bf16x8_t bfrag = *(const bf16x8_t*)&w_s[w * 16 + n][ks + quad * 8];
#pragma unroll
      for (int mt = 0; mt < 2; ++mt) {
        bf16x8_t afrag = *(const bf16x8_t*)&h_s[mt * 16 + n][ks + quad * 8];
        acc[mt] = __builtin_amdgcn_mfma_f32_16x16x32_bf16(afrag, bfrag,
                                                          acc[mt], 0, 0, 0);
      }
    }
    int l = nc * 64 + w * 16 + n;
    float bias = b2[t * L_ + l];
#pragma unroll
    for (int mt = 0; mt < 2; ++mt)
#pragma unroll
      for (int r = 0; r < 4; ++r) {
        float x = acc[mt][r] + bias;
        p_s[mt * 16 + quad * 4 + r][l] = f2bf(1.0f / (1.0f + __expf(-x)));
      }
  }
  __syncthreads();

  // ---------------- routing: (row b, 16-leaf subtree s) ----------------
#pragma unroll
  for (int pass = 0; pass < 4; ++pass) {
    int b = pass * 8 + (tid >> 5);
    int s = tid & 31;
    float P = 1.f;
#pragma unroll
    for (int d = 0; d < 5; ++d) {
      int nd = (1 << d) - 1 + (s >> (5 - d));
      int sd = (s >> (4 - d)) & 1;
      float pv = bf2f(p_s[b][nd]);
      P *= sd ? (1.f - pv) : pv;
    }
    float p5 = bf2f(p_s[b][31 + s]);
    float q5[2] = {P * p5, P * (1.f - p5)};
    float q6[4], q7[8];
#pragma unroll
    for (int j = 0; j < 2; ++j) {
      float pv = bf2f(p_s[b][63 + 2 * s + j]);
      q6[2 * j] = q5[j] * pv;
      q6[2 * j + 1] = q5[j] * (1.f - pv);
    }
#pragma unroll
    for (int u = 0; u < 4; ++u) {
      float pv = bf2f(p_s[b][127 + 4 * s + u]);
      q7[2 * u] = q6[u] * pv;
      q7[2 * u + 1] = q6[u] * (1.f - pv);
    }
    bf16x8_t o0, o1;
#pragma unroll
    for (int v = 0; v < 8; ++v) {
      float pv = bf2f(p_s[b][255 + 8 * s + v]);
      ushort e0 = f2bf(q7[v] * pv);
      ushort e1 = f2bf(q7[v] * (1.f - pv));
      if (v < 4) { o0[2 * v] = (short)e0; o0[2 * v + 1] = (short)e1; }
      else       { o1[2 * (v - 4)] = (short)e0; o1[2 * (v - 4) + 1] = (short)e1; }
    }
    ushort* dst = mu + ((size_t)t * B_ + b0 + b) * L_ + s * 16;
    *(bf16x8_t*)dst = o0;
    *(bf16x8_t*)(dst + 8) = o1;
  }
}

// ---------------------------------------------------------------------------
// k5: MFMA mix: part[t][b][c] = sum_l mu[t][b][l] * lp[t][l][c]
// grid (B/64=16, T), 256 thr. A (mu) direct from global; B (lp) transposed
// into LDS per 64-k chunk. Pitch 68: 8B-aligned dual-b64 loads.
// ---------------------------------------------------------------------------
__global__ __launch_bounds__(256) void k5_mfma(
    const ushort* __restrict__ mu, const ushort* __restrict__ lp,
    float* __restrict__ part) {
  __shared__ ushort bT[CP_ * 68];
  const int t   = blockIdx.y;
  const int m0  = blockIdx.x * 64;
  const int tid = threadIdx.x;
  const int wave = tid >> 6, lane = tid & 63;
  const int quad = lane >> 4;
  const int n    = lane & 15;
  const int mrow = m0 + wave * 16 + n;

  f32x4_t acc[7];
#pragma unroll
  for (int i = 0; i < 7; ++i) acc[i] = (f32x4_t){0.f, 0.f, 0.f, 0.f};

  const ushort* muRow = mu + ((size_t)t * B_ + mrow) * L_;
  const ushort* lp_t  = lp + (size_t)t * L_ * CP_;

  for (int k0 = 0; k0 < L_; k0 += 64) {
    __syncthreads();
#pragma unroll
    for (int i = 0; i < 28; ++i) {
      int e  = i * 256 + tid;
      int kk = e / CP_;
      int c  = e - kk * CP_;
      bT[c * 68 + kk] = lp_t[(size_t)(k0 + kk) * CP_ + c];
    }
    __syncthreads();
#pragma unroll
    for (int ks = 0; ks < 64; ks += 32) {
      bf16x8_t afrag = *(const bf16x8_t*)(muRow + k0 + ks + quad * 8);
#pragma unroll
      for (int nt = 0; nt < 7; ++nt) {
        const ushort* bb = &bT[(nt * 16 + n) * 68 + ks + quad * 8];
        bf16x4_t lo = *(const bf16x4_t*)(bb);
        bf16x4_t hi = *(const bf16x4_t*)(bb + 4);
        bf16x8_t bfrag;
#pragma unroll
        for (int j = 0; j < 4; ++j) { bfrag[j] = lo[j]; bfrag[4 + j] = hi[j]; }
        acc[nt] = __builtin_amdgcn_mfma_f32_16x16x32_bf16(afrag, bfrag, acc[nt], 0, 0, 0);
      }
    }
  }
#pragma unroll
  for (int nt = 0; nt < 7; ++nt) {
    int c = nt * 16 + n;
    if (c < C_) {
#pragma unroll
      for (int r = 0; r < 4; ++r) {
        int m = m0 + wave * 16 + quad * 4 + r;
        part[((size_t)t * B_ + m) * C_ + c] = acc[nt][r];
      }
    }
  }
}

// ---------------------------------------------------------------------------
// k6: out[b][c] = log( (sum_t part[t][b][c]) / (L*T) )
// ---------------------------------------------------------------------------
__global__ __launch_bounds__(256) void k6_log(
    const float* __restrict__ part, float* __restrict__ out) {
  int i = blockIdx.x * 256 + threadIdx.x;
  if (i < B_ * C_) {
    float s = 0.0f;
#pragma unroll
    for (int t = 0; t < T_; ++t) s += part[(size_t)t * B_ * C_ + i];
    out[i] = logf(s * (1.0f / (L_ * T_)));
  }
}

extern "C" void kernel_launch(void* const* d_in, const int* in_sizes, int n_in,
                              void* d_out, int out_size, void* d_ws,
                              size_t ws_size, hipStream_t stream) {
  const float* feat = (const float*)d_in[0];
  const float* W1   = (const float*)d_in[1];
  const float* b1   = (const float*)d_in[2];
  const float* W2   = (const float*)d_in[3];
  const float* b2   = (const float*)d_in[4];
  const float* pi   = (const float*)d_in[5];
  float* out = (float*)d_out;

  char* ws = (char*)d_ws;
  // Disjoint regions, no aliasing: total 29.25 MB.
  ushort* feat_bf  = (ushort*)(ws);                                // 1 MB
  ushort* W1T_buf  = (ushort*)(ws + ((size_t)1 << 20));            // 2 MB
  ushort* W2T_buf  = (ushort*)(ws + ((size_t)3 << 20));            // 2 MB
  ushort* mu_buf   = (ushort*)(ws + ((size_t)5 << 20));            // 16 MB
  ushort* leaf_buf = (ushort*)(ws + ((size_t)21 << 20));           // 1.75 MB
  float*  part_buf = (float*)(ws + ((size_t)23 << 20));            // 6.25 MB

  k_prep<<<4352, 256, 0, stream>>>(feat, W1, W2, pi, feat_bf, W1T_buf,
                                   W2T_buf, leaf_buf);
  k12_mfma<<<dim3(B_ / 32, T_), 256, 0, stream>>>(feat_bf, W1T_buf, b1,
                                                  W2T_buf, b2, mu_buf);
  k5_mfma<<<dim3(B_ / 64, T_), 256, 0, stream>>>(mu_buf, leaf_buf, part_buf);
  k6_log<<<(B_ * C_ + 255) / 256, 256, 0, stream>>>(part_buf, out);
}